// Round 8
// baseline (233.116 us; speedup 1.0000x reference)
//
#include <hip/hip_runtime.h>
#include <hip/hip_bf16.h>

#define BB 2
#define CC 128
#define NN 4096
#define KK 20

// workspace offsets, in floats
#define WS_FCACC  16
#define WS_FS     1024
#define WS_X      8192
#define WS_XX     32768
#define WS_P      65536
#define WS_Q      1114112
#define WS_FE     2326528
#define WS_F12    3375104

struct InPtrs { const void* p[22]; };

__device__ __forceinline__ int detect_bf16(const void* xyz) {
  const unsigned* u = (const unsigned*)xyz;
  int cnt = 0;
  for (int i = 0; i < 64; ++i) {
    unsigned lo = u[i] & 0x7FFFu;
    cnt += (lo >= 0x3C00u && lo <= 0x4100u) ? 1 : 0;
  }
  return cnt >= 32;
}

__device__ __forceinline__ float ldin(const void* p, long long i, int flag) {
  if (flag) {
    unsigned short b = ((const unsigned short*)p)[i];
    return __uint_as_float(((unsigned)b) << 16);
  }
  return ((const float*)p)[i];
}

// f64 key: (sortable32(pd) << 12) | (4095 - m), exact integer <= 2^44.
// Higher key = larger pd, ties broken toward lower index m (matches lax.top_k).
__device__ __forceinline__ double dkey(float v, int m) {
  unsigned u = __float_as_uint(v);
  u = (u & 0x80000000u) ? ~u : (u | 0x80000000u);
  return (double)u * 4096.0 + (double)((NN - 1) - m);
}

__device__ __forceinline__ void insert4d(double key,
    double& a0, double& a1, double& a2, double& a3) {
  bool b0 = key > a0, b1 = key > a1, b2 = key > a2, b3 = key > a3;
  a3 = b3 ? (b2 ? a2 : key) : a3;
  a2 = b2 ? (b1 ? a1 : key) : a2;
  a1 = b1 ? (b0 ? a0 : key) : a1;
  a0 = b0 ? key : a0;
}

// ---------------- k1: X/XX convert + P,Q projections (all inputs inline) ------
// 256 blocks; block = 32 points; wave w covers o in [w*16,w*16+16);
// sub=(t>>5)&1 -> o-subrange sub*8..+8; mloc = t&31 is the point.
__global__ __launch_bounds__(256) void k1_pq(InPtrs in, float* ws) {
  __shared__ float ldsW[64 * 128];   // staged W2 half  (32 KB)
  __shared__ float ldsF[64 * 32];    // staged F half   (8 KB)
  __shared__ float sS1[64], sC1[64], sS2[64], sC2[64], sW1[384];
  int flag = detect_bf16(in.p[0]);
  int t = threadIdx.x;
  int bid = blockIdx.x;
  // --- prologue A: grid-stride X convert + XX (blocks 0..31 active) ---
  {
    int gid = bid * 256 + t;
    if (gid < BB * NN) {
      int b = gid >> 12, m = gid & (NN - 1);
      long long xb = (long long)b * 3 * NN;
      float x0 = ldin(in.p[0], xb + m, flag);
      float x1 = ldin(in.p[0], xb + NN + m, flag);
      float x2 = ldin(in.p[0], xb + 2 * NN + m, flag);
      ws[WS_X + xb + m] = x0;
      ws[WS_X + xb + NN + m] = x1;
      ws[WS_X + xb + 2 * NN + m] = x2;
      ws[WS_XX + gid] =
        __fadd_rn(__fadd_rn(__fmul_rn(x0, x0), __fmul_rn(x1, x1)), __fmul_rn(x2, x2));
    }
    if (bid == 0 && t < 16) ws[WS_FCACC + t] = 0.f;   // zero accum for k23 atomics
  }
  // --- prologue B: fold BN constants + stage W1 into LDS ---
  if (t < 64) {
    float g1 = ldin(in.p[4], t, flag), v1 = ldin(in.p[7], t, flag);
    float s1 = g1 / sqrtf(v1 + 1e-5f);
    float b1 = ldin(in.p[3], t, flag), be1 = ldin(in.p[5], t, flag), m1v = ldin(in.p[6], t, flag);
    sS1[t] = s1; sC1[t] = s1 * (b1 - m1v) + be1;
    float g2 = ldin(in.p[10], t, flag), v2 = ldin(in.p[13], t, flag);
    float s2 = g2 / sqrtf(v2 + 1e-5f);
    float b2 = ldin(in.p[9], t, flag), be2 = ldin(in.p[11], t, flag), m2v = ldin(in.p[12], t, flag);
    sS2[t] = s2; sC2[t] = s2 * (b2 - m2v) + be2;
  }
  for (int i = t; i < 384; i += 256) sW1[i] = ldin(in.p[2], i, flag);
  // --- main GEMM: two c-halves, W2+F staged from inputs ---
  int b = bid >> 7;
  int m0 = (bid & 127) << 5;
  int w = t >> 6, sub = (t >> 5) & 1, mloc = t & 31;
  const void* Fin = in.p[1];
  const void* W2in = in.p[8];
  long long fb = (long long)b * CC * NN;
  float accP[8], accQ[8];
#pragma unroll
  for (int j = 0; j < 8; ++j) { accP[j] = 0.f; accQ[j] = 0.f; }
  for (int half = 0; half < 2; ++half) {
    if (half) __syncthreads();
    for (int i = t; i < 64 * 128; i += 256) {
      int o = i >> 7, r = i & 127;
      int c = (r & 63) + half * 64 + ((r >> 6) << 7);   // +128 selects Q columns
      ldsW[i] = ldin(W2in, o * 256 + c, flag);
    }
    for (int i = t; i < 64 * 32; i += 256) {
      int cl = i >> 5, ml = i & 31;
      ldsF[i] = ldin(Fin, fb + (long long)(half * 64 + cl) * NN + m0 + ml, flag);
    }
    __syncthreads();
    for (int cl = 0; cl < 64; ++cl) {
      float f = ldsF[cl * 32 + mloc];
#pragma unroll
      for (int j = 0; j < 8; ++j) {
        int o = w * 16 + sub * 8 + j;
        accP[j] = fmaf(ldsW[o * 128 + cl], f, accP[j]);
        accQ[j] = fmaf(ldsW[o * 128 + 64 + cl], f, accQ[j]);
      }
    }
  }
  // --- epilogue: xyz part + BN fold, write P/Q ---
  int m = m0 + mloc;
  long long xb = (long long)b * 3 * NN;
  float x0 = ldin(in.p[0], xb + m, flag);
  float x1 = ldin(in.p[0], xb + NN + m, flag);
  float x2 = ldin(in.p[0], xb + 2 * NN + m, flag);
  float* P = ws + WS_P + ((long long)(b * NN + m)) * 128;
  float* Q = ws + WS_Q + ((long long)(b * NN + m)) * 128;
#pragma unroll
  for (int j = 0; j < 8; ++j) {
    int o = w * 16 + sub * 8 + j;
    float s1 = sS1[o], c1 = sC1[o];
    float px = fmaf(sW1[o * 6 + 2], x2, fmaf(sW1[o * 6 + 1], x1, sW1[o * 6 + 0] * x0));
    float qx = fmaf(sW1[o * 6 + 5], x2, fmaf(sW1[o * 6 + 4], x1, sW1[o * 6 + 3] * x0));
    P[o] = s1 * px;
    Q[o] = fmaf(s1, qx - px, c1);
    float s2 = sS2[o], c2 = sC2[o];
    P[64 + o] = s2 * accP[j];
    Q[64 + o] = fmaf(s2, accQ[j] - accP[j], c2);
  }
}

// ------- k23: KNN top-20 (one wave/pt) + gather/max-pool + down-proj ----------
__global__ __launch_bounds__(256) void k23_knn_fenc_down(InPtrs in, float* ws) {
  __shared__ float ldsW[32 * 129];   // WD1|WD2 staged (16.5 KB)
  __shared__ float ldsFE[4 * 128];
  __shared__ float ldsFC[16];
  int flag = detect_bf16(in.p[0]);
  int t = threadIdx.x;
  int w = t >> 6, lane = t & 63;
  int pt = blockIdx.x * 4 + w;                // 2048 blocks, 1 wave = 1 point
  int b = pt >> 12;
  int n = pt & (NN - 1);
  // stage down-proj weights (consumed after the post-FE barrier)
  for (int i = t; i < 32 * 128; i += 256) {
    int o = i >> 7, c = i & 127;
    ldsW[o * 129 + c] = (o < 16) ? ldin(in.p[14], o * 128 + c, flag)
                                 : ldin(in.p[15], (o - 16) * 128 + c, flag);
  }
  if (t < 16) ldsFC[t] = 0.f;
  // ---- KNN core (round-7-verified, X/XX from ws) ----
  const float* X = ws + WS_X + (long long)b * 3 * NN;
  const float* XX = ws + WS_XX + (long long)b * NN;
  float xc0 = X[n], xc1 = X[NN + n], xc2 = X[2 * NN + n], xxn = XX[n];
  double a0 = -1.0, a1 = -1.0, a2 = -1.0, a3 = -1.0;
#pragma unroll 4
  for (int s = 0; s < 64; ++s) {
    int m = s * 64 + lane;
    float c0 = X[m], c1 = X[NN + m], c2 = X[2 * NN + m], xxm = XX[m];
    float inner = __fadd_rn(__fadd_rn(__fmul_rn(c0, xc0), __fmul_rn(c1, xc1)), __fmul_rn(c2, xc2));
    float pd = __fsub_rn(__fsub_rn(__fmul_rn(2.0f, inner), xxn), xxm);
    insert4d(dkey(pd, m), a0, a1, a2, a3);
  }
  unsigned long long used = 0;
  int nv = 4;
  double winner = 0.0;                        // lane r keeps round-r winner
  for (int r = 0; r < KK; ++r) {
    double v = a0;
#pragma unroll
    for (int off = 1; off < 64; off <<= 1)
      v = fmax(v, __shfl_xor(v, off));
    if (lane == r) winner = v;
    if (a0 == v) {                            // unique owner (idx embedded in key)
      unsigned hi = (unsigned)(v * (1.0 / 4096.0));
      double rem = v - 4096.0 * (double)hi;
      int mm = (NN - 1) - (int)rem;
      used |= 1ull << (mm >> 6);
      a0 = a1; a1 = a2; a2 = a3; a3 = -1.0; --nv;
      if (nv == 0) {                          // rare: lane supplied >=5 winners
        a0 = a1 = a2 = a3 = -1.0;
#pragma unroll 1
        for (int s = 0; s < 64; ++s) {
          if (!((used >> s) & 1ull)) {
            int m = s * 64 + lane;
            float c0 = X[m], c1 = X[NN + m], c2 = X[2 * NN + m], xxm = XX[m];
            float inner = __fadd_rn(__fadd_rn(__fmul_rn(c0, xc0), __fmul_rn(c1, xc1)), __fmul_rn(c2, xc2));
            float pd = __fsub_rn(__fsub_rn(__fmul_rn(2.0f, inner), xxn), xxm);
            insert4d(dkey(pd, m), a0, a1, a2, a3);
          }
        }
        nv = 4;
      }
    }
  }
  int myidx;
  {
    unsigned hi = (unsigned)(winner * (1.0 / 4096.0));
    double rem = winner - 4096.0 * (double)hi;
    myidx = (NN - 1) - (int)rem;
  }
  // ---- gather + max-pool ----
  const float* Q = ws + WS_Q + (long long)pt * 128;
  const float* Pb = ws + WS_P + (long long)b * NN * 128;
  float2 q = ((const float2*)Q)[lane];
  float mx0 = -3.4e38f, mx1 = -3.4e38f;
#pragma unroll
  for (int j = 0; j < KK; ++j) {
    int id = __shfl(myidx, j);
    float2 p = ((const float2*)(Pb + (long long)id * 128))[lane];
    mx0 = fmaxf(mx0, p.x + q.x);
    mx1 = fmaxf(mx1, p.y + q.y);
  }
  float2 fe = make_float2(fmaxf(mx0, 0.f), fmaxf(mx1, 0.f));
  ((float2*)(ws + WS_FE + (long long)pt * 128))[lane] = fe;
  ((float2*)(ldsFE + w * 128))[lane] = fe;
  __syncthreads();
  // ---- down-projections: 2 lanes per (point w, oid); halves joined by shfl ----
  int oid = lane & 31, hf = lane >> 5;
  float acc = 0.f;
#pragma unroll 8
  for (int cl = 0; cl < 64; ++cl)
    acc = fmaf(ldsW[oid * 129 + hf * 64 + cl], ldsFE[w * 128 + hf * 64 + cl], acc);
  acc += __shfl_xor(acc, 32);
  float v = fmaxf(acc, 0.f);
  if (hf == 0) ws[WS_F12 + (long long)pt * 32 + oid] = v;
  if (b == 0) {
    if (hf == 1 && oid >= 16) {               // lanes 48..63: f_space sum over f2
      float s = v;
#pragma unroll
      for (int d = 1; d < 16; d <<= 1) s += __shfl_xor(s, d);
      if (oid == 16) ws[WS_FS + n] = s * 0.0625f;
    }
    if (hf == 0 && oid < 16) atomicAdd(&ldsFC[oid], v);
  }
  __syncthreads();
  if (b == 0 && t < 16) atomicAdd(ws + WS_FCACC + t, ldsFC[t]);
}

// ---------------- k5: outer-sqrt + up-proj + BN + Mish -> output --------------
__global__ __launch_bounds__(256) void k5_final(InPtrs in, float* ws,
                                                float* outf, __hip_bfloat16* outb) {
  __shared__ float fin[16 * 16];
  __shared__ float sWUP[2048];
  __shared__ float sSU[128], sCU[128];
  int flag = detect_bf16(in.p[0]);
  int t = threadIdx.x;
  int g = t >> 4;        // 0..15 : output group of 8
  int p = t & 15;        // point within tile
  int b = blockIdx.x >> 8;
  int n0 = (blockIdx.x & 255) << 4;
  int n = n0 + p;
  for (int i = t; i < 2048; i += 256) sWUP[i] = ldin(in.p[16], i, flag);
  if (t < 128) {
    float gu = ldin(in.p[18], t, flag), vu = ldin(in.p[21], t, flag);
    float su = gu / sqrtf(vu + 1e-5f);
    float bu = ldin(in.p[17], t, flag), beu = ldin(in.p[19], t, flag), mu = ldin(in.p[20], t, flag);
    sSU[t] = su; sCU[t] = su * (bu - mu) + beu;
  }
  {
    float fs = ws[WS_FS + n];
    float fc = ws[WS_FCACC + g] * (1.0f / NN);
    float f1v = ws[WS_F12 + (long long)(b * NN + n) * 32 + g];
    float f2v = ws[WS_F12 + (long long)(b * NN + n) * 32 + 16 + g];
    fin[p * 16 + g] = sqrtf(fc * fs + 1e-12f) + f1v + f2v;
  }
  __syncthreads();
  const float4* FE4 = (const float4*)(ws + WS_FE + (long long)(b * NN + n) * 128 + g * 8);
  float fev[8];
  {
    float4 a = FE4[0], c = FE4[1];
    fev[0] = a.x; fev[1] = a.y; fev[2] = a.z; fev[3] = a.w;
    fev[4] = c.x; fev[5] = c.y; fev[6] = c.z; fev[7] = c.w;
  }
#pragma unroll
  for (int j = 0; j < 8; ++j) {
    int o = g * 8 + j;
    float acc = 0.f;
#pragma unroll
    for (int c = 0; c < 16; ++c)
      acc = fmaf(sWUP[o * 16 + c], fin[p * 16 + c], acc);
    float fo = fmaf(sSU[o], acc, sCU[o]);
    fo = fmaxf(fo, 0.f);
    float fl = fev[j] - fo;
    // Mish(x) = x*(u^2+2u)/(u^2+2u+2), u=e^x; exact for x<=15, y=x beyond
    float u = __expf(fl);
    float nmr = u * (u + 2.f);
    float y = fl * __fdividef(nmr, nmr + 2.f);
    if (fl > 15.f) y = fl;
    long long oi = ((long long)b * CC + o) * NN + n;
    if (flag) outb[oi] = __float2bfloat16(y);
    else      outf[oi] = y;
  }
}

extern "C" void kernel_launch(void* const* d_in, const int* in_sizes, int n_in,
                              void* d_out, int out_size, void* d_ws, size_t ws_size,
                              hipStream_t stream) {
  (void)in_sizes; (void)out_size; (void)ws_size;
  float* ws = (float*)d_ws;
  InPtrs ip;
  for (int i = 0; i < 22; ++i) ip.p[i] = (i < n_in) ? d_in[i] : nullptr;
  hipLaunchKernelGGL(k1_pq,              dim3(256),          dim3(256), 0, stream, ip, ws);
  hipLaunchKernelGGL(k23_knn_fenc_down,  dim3(BB * NN / 4),  dim3(256), 0, stream, ip, ws);
  hipLaunchKernelGGL(k5_final,           dim3(BB * NN / 16), dim3(256), 0, stream, ip, ws,
                     (float*)d_out, (__hip_bfloat16*)d_out);
}